// Round 4
// baseline (1230.025 us; speedup 1.0000x reference)
//
#include <hip/hip_runtime.h>

typedef unsigned short u16;
typedef unsigned int   u32;
typedef _Float16 f16;
typedef __attribute__((ext_vector_type(8))) _Float16 half8;
typedef __attribute__((ext_vector_type(4))) float f32x4;

#define NBATCH 16384

__device__ __forceinline__ u16 f2h(float x) {
  union { f16 h; u16 u; } v; v.h = (f16)x; return v.u;
}

// ---------- prep: transpose fp32 (M x N) -> f16 (N x M), 16 mats (z = layer*2 + net)
// Single launch; blockIdx.x segments: [0,16) W1 | [16,272) W2 | [272,288) W3.
__global__ __launch_bounds__(256) void cvt_all(
    const float* __restrict__ tW1, const float* __restrict__ sW1,
    const float* __restrict__ tW2, const float* __restrict__ sW2,
    const float* __restrict__ tW3, const float* __restrict__ sW3,
    u16* __restrict__ dW1, u16* __restrict__ dW2, u16* __restrict__ dW3)
{
  __shared__ float tile[32][33];
  const int z = blockIdx.z, bx = blockIdx.x;
  const float *tsrc, *ssrc; u16* dst; int M, N, nt, mt;
  if (bx < 16)       { tsrc = tW1; ssrc = sW1; dst = dW1; M = 32;  N = 512; nt = bx;           mt = 0; }
  else if (bx < 272) { tsrc = tW2; ssrc = sW2; dst = dW2; M = 512; N = 512; nt = (bx - 16) & 15; mt = (bx - 16) >> 4; }
  else               { tsrc = tW3; ssrc = sW3; dst = dW3; M = 512; N = 32;  nt = 0;            mt = bx - 272; }
  const float* src = ((z & 1) ? ssrc : tsrc) + (size_t)(z >> 1) * M * N;
  u16* d = dst + (size_t)z * M * N;
  const int n0 = nt * 32, m0 = mt * 32;
  for (int r = 0; r < 4; r++) {
    int m = m0 + threadIdx.y + r * 8, n = n0 + threadIdx.x;
    tile[threadIdx.y + r * 8][threadIdx.x] = src[(size_t)m * N + n];
  }
  __syncthreads();
  for (int r = 0; r < 4; r++) {
    int n = n0 + threadIdx.y + r * 8, m = m0 + threadIdx.x;
    d[(size_t)n * M + m] = f2h(tile[threadIdx.x][threadIdx.y + r * 8]);
  }
}

// ---------- fused RealNVP: 1 block = 64 rows, 512 threads, 8 waves, 256 blocks.
// Pinned at 2 waves/SIMD (unified VGPR/AGPR file). R3's depth-4 bb[4][4]
// spilled to scratch in the K-loop (WRITE_SIZE 21->59 MB, time 406->445).
// R4 fixes: depth-3 bb[3][4] (48 regs, no cur copy; refill slot ci%3 with
// chunk ci+3 AFTER its MFMAs -> ~2.1-iter latency coverage, no spill), and
// quad-staggered epilogue stores (ctx=(ct+quad)&3) to kill the constant
// 1.15e7 LDS bank conflicts from 4-way quad aliasing on ds_write_b16.
// Wave w owns cols [w*64,+64). z/log_det in registers: thread t owns row
// (t>>3), cols [(t&7)*8, +8).
__global__ __launch_bounds__(512, 2) void meganvp(
    const float* __restrict__ y,
    const u16* __restrict__ W1T, const u16* __restrict__ W2T, const u16* __restrict__ W3T,
    const float* __restrict__ tb1, const float* __restrict__ sb1,
    const float* __restrict__ tb2, const float* __restrict__ sb2,
    const float* __restrict__ tb3, const float* __restrict__ sb3,
    const float* __restrict__ s_scale, const float* __restrict__ s_shift,
    float* __restrict__ out)
{
  __shared__ u16 bufA[64 * 512];    // 64 KB: H1 (XOR-swizzled chunks)
  __shared__ u16 bufB[64 * 512];    // 64 KB: H2
  __shared__ u16 X[64 * 40];        // 5 KB: f16 pass-through half
  __shared__ float TS[64 * 68];     // 17 KB: coupling (t,s) pairs, 16B-aligned rows

  const int t = threadIdx.x;
  const int m0 = blockIdx.x * 64;
  const int lane = t & 63, w = t >> 6, lm = lane & 15, quad = lane >> 4;
  const int cw = w * 64;                       // wave's 64-col slice
  const int phase = blockIdx.x & 15;
  const int zr = t >> 3, zq = t & 7, c0 = zq * 8;

  float z[8], ld[8];
  {
    const float* yb = y + (size_t)(m0 + zr) * 64 + c0;
    f32x4 v0 = *(const f32x4*)&yb[0];
    f32x4 v1 = *(const f32x4*)&yb[4];
#pragma unroll
    for (int k = 0; k < 4; k++) { z[k] = v0[k]; z[4 + k] = v1[k]; }
#pragma unroll
    for (int e = 0; e < 8; e++) ld[e] = 0.f;
  }

  for (int layer = 0; layer < 8; layer++) {
    const int par = layer & 1;
    { // X build: 4 pass-through f16 per thread
      union { u16 a[4]; uint2 v; } xv;
#pragma unroll
      for (int e = 0; e < 4; e++) xv.a[e] = f2h(z[2 * e + 1 - par]);
      *(uint2*)&X[zr * 40 + zq * 4] = xv.v;
    }
    __syncthreads();                          // X visible (also fences prev coupling TS reads)

    for (int net = 0; net < 2; net++) {
      const int idx = layer * 2 + net;

      // ---- H1 = relu(X @ W1 + b1), K=32, wave cols [cw, cw+64) -> bufA
      {
        const float* b1p = (net ? sb1 : tb1) + layer * 512 + cw + lm;
        float bias1[4];
#pragma unroll
        for (int ct = 0; ct < 4; ct++) bias1[ct] = b1p[ct * 16];
        const u16* W1p = W1T + ((size_t)idx * 512 + cw + lm) * 32 + quad * 8;
        half8 bv[4];
#pragma unroll
        for (int ct = 0; ct < 4; ct++) bv[ct] = *(const half8*)&W1p[ct * 512];
        half8 av[4];
#pragma unroll
        for (int rt = 0; rt < 4; rt++)
          av[rt] = *(const half8*)&X[(rt * 16 + lm) * 40 + quad * 8];
        f32x4 zz = {0.f, 0.f, 0.f, 0.f};
        f32x4 acc[4][4];
#pragma unroll
        for (int rt = 0; rt < 4; rt++)
#pragma unroll
          for (int ct = 0; ct < 4; ct++)
            acc[rt][ct] = __builtin_amdgcn_mfma_f32_16x16x32_f16(av[rt], bv[ct], zz, 0, 0, 0);
        // bufA is free here: prev net's H2 reads of bufA completed before its bar2
        // quad-staggered store order: instruction (rt,ct,r) mixes 4 col-tiles
        // across quads -> spreads XOR-swizzle slots -> no 4-way bank aliasing
#pragma unroll
        for (int rt = 0; rt < 4; rt++) {
          const int mrow = rt * 16 + quad * 4;
#pragma unroll
          for (int ct = 0; ct < 4; ct++) {
            const int ctx = (ct + quad) & 3;
            const int n = cw + ctx * 16 + lm;
#pragma unroll
            for (int r = 0; r < 4; r++) {
              float v = acc[rt][ctx][r] + bias1[ctx];
              v = v > 0.f ? v : 0.f;
              const int m = mrow + r;
              bufA[m * 512 + ((((n >> 3) ^ (m & 7)) << 3) | (n & 7))] = f2h(v);
            }
          }
        }
      }
      __syncthreads();                        // bar1: H1 written -> H2 reads

      // ---- H2 = relu(H1 @ W2 + b2), K=512, W2 streamed, depth-3 rotating prefetch
      {
        const float* b2p = (net ? sb2 : tb2) + layer * 512 + cw + lm;
        float bias2[4];
#pragma unroll
        for (int ct = 0; ct < 4; ct++) bias2[ct] = b2p[ct * 16];
        const u16* W2p = W2T + ((size_t)idx * 512 + cw + lm) * 512 + quad * 8;
        f32x4 zz = {0.f, 0.f, 0.f, 0.f};
        f32x4 acc[4][4];
#pragma unroll
        for (int rt = 0; rt < 4; rt++)
#pragma unroll
          for (int ct = 0; ct < 4; ct++) acc[rt][ct] = zz;
        half8 bb[3][4];                       // depth-3 rotating prefetch (48 VGPR)
#pragma unroll
        for (int p = 0; p < 3; p++) {
          const int kp = ((p + phase) & 15) * 32;
#pragma unroll
          for (int ct = 0; ct < 4; ct++)
            bb[p][ct] = *(const half8*)&W2p[ct * 8192 + kp];
        }
#pragma unroll
        for (int ci = 0; ci < 16; ci++) {
          const int kk = ((ci + phase) & 15) * 32;
          half8 av[4];
#pragma unroll
          for (int rt = 0; rt < 4; rt++) {
            const int m = rt * 16 + lm;
            av[rt] = *(const half8*)&bufA[m * 512 + ((((kk >> 3) + quad) ^ (m & 7)) << 3)];
          }
#pragma unroll
          for (int rt = 0; rt < 4; rt++)
#pragma unroll
            for (int ct = 0; ct < 4; ct++)
              acc[rt][ct] = __builtin_amdgcn_mfma_f32_16x16x32_f16(av[rt], bb[ci % 3][ct], acc[rt][ct], 0, 0, 0);
          if (ci < 13) {                      // refill consumed slot with chunk ci+3
            const int kn = ((ci + 3 + phase) & 15) * 32;
#pragma unroll
            for (int ct = 0; ct < 4; ct++)
              bb[ci % 3][ct] = *(const half8*)&W2p[ct * 8192 + kn];
          }
        }
        // epilogue writes bufB -> no in-place barrier needed; quad-staggered
#pragma unroll
        for (int rt = 0; rt < 4; rt++) {
          const int mrow = rt * 16 + quad * 4;
#pragma unroll
          for (int ct = 0; ct < 4; ct++) {
            const int ctx = (ct + quad) & 3;
            const int n = cw + ctx * 16 + lm;
#pragma unroll
            for (int r = 0; r < 4; r++) {
              float v = acc[rt][ctx][r] + bias2[ctx];
              v = v > 0.f ? v : 0.f;
              const int m = mrow + r;
              bufB[m * 512 + ((((n >> 3) ^ (m & 7)) << 3) | (n & 7))] = f2h(v);
            }
          }
        }
      }
      __syncthreads();                        // bar2: bufB visible; bufA reads all done

      // ---- head: wave w -> rows [(w&3)*16,+16), col tile (w>>2)*16, K=512
      {
        const int hr = (w & 3) * 16, hc = (w >> 2) * 16;
        const u16* W3p = W3T + ((size_t)idx * 32 + hc + lm) * 512 + quad * 8;
        f32x4 ha[2];
        ha[0] = (f32x4){0.f, 0.f, 0.f, 0.f}; ha[1] = ha[0];
        const int m = hr + lm;
        half8 pv[4];                          // depth-4 W3 prefetch
#pragma unroll
        for (int p = 0; p < 4; p++)
          pv[p] = *(const half8*)&W3p[((p + phase) & 15) * 32];
#pragma unroll
        for (int ci = 0; ci < 16; ci++) {
          const int kk = ((ci + phase) & 15) * 32;
          half8 av = *(const half8*)&bufB[m * 512 + ((((kk >> 3) + quad) ^ (m & 7)) << 3)];
          ha[ci & 1] = __builtin_amdgcn_mfma_f32_16x16x32_f16(av, pv[ci & 3], ha[ci & 1], 0, 0, 0);
          if (ci < 12)
            pv[ci & 3] = *(const half8*)&W3p[((ci + 4 + phase) & 15) * 32];
        }
        const int j = hc + lm;
        if (net == 0) {
          const float b3 = tb3[layer * 32 + j];
#pragma unroll
          for (int r = 0; r < 4; r++) {
            const int mm = hr + quad * 4 + r;
            TS[mm * 68 + 2 * j] = ha[0][r] + ha[1][r] + b3;
          }
        } else {
          const int jj = layer * 32 + j;
          const float b3 = sb3[jj], sc = s_scale[jj], sh = s_shift[jj];
#pragma unroll
          for (int r = 0; r < 4; r++) {
            const int mm = hr + quad * 4 + r;
            TS[mm * 68 + 2 * j + 1] = tanhf(ha[0][r] + ha[1][r] + b3) * sc + sh;
          }
        }
      }
      __syncthreads();                        // bar3: bufB reads done; TS visible
    } // net

    // ---- coupling: thread reads its 4 (t,s) pairs, updates z/ld in registers.
    // (No trailing barrier: next layer's X barrier orders these TS reads
    //  before the next head's TS writes.)
    {
      const float* base = &TS[zr * 68 + zq * 8];
      f32x4 q0 = *(const f32x4*)&base[0];
      f32x4 q1 = *(const f32x4*)&base[4];
      float q[8];
#pragma unroll
      for (int k = 0; k < 4; k++) { q[k] = q0[k]; q[4 + k] = q1[k]; }
#pragma unroll
      for (int e = 0; e < 4; e++) {
        const float tv = q[2 * e], sv = q[2 * e + 1];
        const int zi = 2 * e + par;
        z[zi] = z[zi] * expf(sv) + tv;
        ld[zi] += sv;
      }
    }
  } // layer

  // ---- store z and log_det
  {
    float* zb = out + (size_t)(m0 + zr) * 64 + c0;
    float* lb = out + (size_t)NBATCH * 64 + (size_t)(m0 + zr) * 64 + c0;
    f32x4 v0, v1, l0, l1;
#pragma unroll
    for (int k = 0; k < 4; k++) {
      v0[k] = z[k]; v1[k] = z[4 + k];
      l0[k] = ld[k]; l1[k] = ld[4 + k];
    }
    *(f32x4*)&zb[0] = v0; *(f32x4*)&zb[4] = v1;
    *(f32x4*)&lb[0] = l0; *(f32x4*)&lb[4] = l1;
  }
}

extern "C" void kernel_launch(void* const* d_in, const int* in_sizes, int n_in,
                              void* d_out, int out_size, void* d_ws, size_t ws_size,
                              hipStream_t stream) {
  (void)in_sizes; (void)n_in; (void)out_size; (void)ws_size;
  const float* y   = (const float*)d_in[0];
  const float* tW1 = (const float*)d_in[1];
  const float* tb1 = (const float*)d_in[2];
  const float* tW2 = (const float*)d_in[3];
  const float* tb2 = (const float*)d_in[4];
  const float* tW3 = (const float*)d_in[5];
  const float* tb3 = (const float*)d_in[6];
  const float* sW1 = (const float*)d_in[7];
  const float* sb1 = (const float*)d_in[8];
  const float* sW2 = (const float*)d_in[9];
  const float* sb2 = (const float*)d_in[10];
  const float* sW3 = (const float*)d_in[11];
  const float* sb3 = (const float*)d_in[12];
  const float* s_scale = (const float*)d_in[13];
  const float* s_shift = (const float*)d_in[14];
  float* out = (float*)d_out;

  char* ws = (char*)d_ws;
  const size_t W1SZ = (size_t)16 * 512 * 32 * 2;    // 524288
  const size_t W2SZ = (size_t)16 * 512 * 512 * 2;   // 8388608
  u16* W1 = (u16*)(ws);
  u16* W2 = (u16*)(ws + W1SZ);
  u16* W3 = (u16*)(ws + W1SZ + W2SZ);

  cvt_all<<<dim3(288, 1, 16), dim3(32, 8), 0, stream>>>(tW1, sW1, tW2, sW2, tW3, sW3,
                                                        W1, W2, W3);

  meganvp<<<256, 512, 0, stream>>>(y, W1, W2, W3, tb1, sb1, tb2, sb2, tb3, sb3,
                                   s_scale, s_shift, out);
}

// Round 6
// 436.317 us; speedup vs baseline: 2.8191x; 2.8191x over previous
//
#include <hip/hip_runtime.h>

typedef unsigned short u16;
typedef unsigned int   u32;
typedef _Float16 f16;
typedef __attribute__((ext_vector_type(8))) _Float16 half8;
typedef __attribute__((ext_vector_type(4))) float f32x4;

#define NBATCH 16384

__device__ __forceinline__ u16 f2h(float x) {
  union { f16 h; u16 u; } v; v.h = (f16)x; return v.u;
}

// ---------- prep: transpose fp32 (M x N) -> f16 (N x M), 16 mats (z = layer*2 + net)
// Single launch; blockIdx.x segments: [0,16) W1 | [16,272) W2 | [272,288) W3.
__global__ __launch_bounds__(256) void cvt_all(
    const float* __restrict__ tW1, const float* __restrict__ sW1,
    const float* __restrict__ tW2, const float* __restrict__ sW2,
    const float* __restrict__ tW3, const float* __restrict__ sW3,
    u16* __restrict__ dW1, u16* __restrict__ dW2, u16* __restrict__ dW3)
{
  __shared__ float tile[32][33];
  const int z = blockIdx.z, bx = blockIdx.x;
  const float *tsrc, *ssrc; u16* dst; int M, N, nt, mt;
  if (bx < 16)       { tsrc = tW1; ssrc = sW1; dst = dW1; M = 32;  N = 512; nt = bx;           mt = 0; }
  else if (bx < 272) { tsrc = tW2; ssrc = sW2; dst = dW2; M = 512; N = 512; nt = (bx - 16) & 15; mt = (bx - 16) >> 4; }
  else               { tsrc = tW3; ssrc = sW3; dst = dW3; M = 512; N = 32;  nt = 0;            mt = bx - 272; }
  const float* src = ((z & 1) ? ssrc : tsrc) + (size_t)(z >> 1) * M * N;
  u16* d = dst + (size_t)z * M * N;
  const int n0 = nt * 32, m0 = mt * 32;
  for (int r = 0; r < 4; r++) {
    int m = m0 + threadIdx.y + r * 8, n = n0 + threadIdx.x;
    tile[threadIdx.y + r * 8][threadIdx.x] = src[(size_t)m * N + n];
  }
  __syncthreads();
  for (int r = 0; r < 4; r++) {
    int n = n0 + threadIdx.y + r * 8, m = m0 + threadIdx.x;
    d[(size_t)n * M + m] = f2h(tile[threadIdx.x][threadIdx.y + r * 8]);
  }
}

// ---------- fused RealNVP: 1 block = 64 rows, 512 threads, 8 waves, 256 blocks.
// Pinned at 2 waves/SIMD. R4's runtime-indexed acc (ctx=(ct+quad)&3) hit guide
// rule #20 -> whole acc array in scratch -> 4 GB HBM traffic. Reverted.
// R5 structural epilogue fix: SWAPPED MFMA OPERANDS. A-frag and B-frag share
// the same lane->(outer,k) mapping, so mfma(w_frag, h_frag) yields the
// transposed tile: lane owns row m=lm, cols n=quad*4+g (g=reg). All loads stay
// byte-identical; epilogue becomes 16 ds_write_b64 (was 64 ds_write_b16) per
// thread per GEMM with an exactly bank-balanced write pattern (4 dwords/bank,
// the HW minimum). Biases become f32x4 vector loads. Depth-3 W2 prefetch
// (static bb[ci%3] under full unroll), depth-4 W3 prefetch, split bufA/bufB.
// (R5 bench was an infra failure - container died at acquire; kernel re-audited:
// uniform barriers, static indexing, 8B-aligned LDS writes. Resubmitted as-is.)
__global__ __launch_bounds__(512, 2) void meganvp(
    const float* __restrict__ y,
    const u16* __restrict__ W1T, const u16* __restrict__ W2T, const u16* __restrict__ W3T,
    const float* __restrict__ tb1, const float* __restrict__ sb1,
    const float* __restrict__ tb2, const float* __restrict__ sb2,
    const float* __restrict__ tb3, const float* __restrict__ sb3,
    const float* __restrict__ s_scale, const float* __restrict__ s_shift,
    float* __restrict__ out)
{
  __shared__ u16 bufA[64 * 512];    // 64 KB: H1 (XOR-swizzled chunks)
  __shared__ u16 bufB[64 * 512];    // 64 KB: H2
  __shared__ u16 X[64 * 40];        // 5 KB: f16 pass-through half
  __shared__ float TS[64 * 68];     // 17 KB: coupling (t,s) pairs, 16B-aligned rows

  const int t = threadIdx.x;
  const int m0 = blockIdx.x * 64;
  const int lane = t & 63, w = t >> 6, lm = lane & 15, quad = lane >> 4;
  const int cw = w * 64;                       // wave's 64-col slice
  const int phase = blockIdx.x & 15;
  const int zr = t >> 3, zq = t & 7, c0 = zq * 8;

  float z[8], ld[8];
  {
    const float* yb = y + (size_t)(m0 + zr) * 64 + c0;
    f32x4 v0 = *(const f32x4*)&yb[0];
    f32x4 v1 = *(const f32x4*)&yb[4];
#pragma unroll
    for (int k = 0; k < 4; k++) { z[k] = v0[k]; z[4 + k] = v1[k]; }
#pragma unroll
    for (int e = 0; e < 8; e++) ld[e] = 0.f;
  }

  for (int layer = 0; layer < 8; layer++) {
    const int par = layer & 1;
    { // X build: 4 pass-through f16 per thread
      union { u16 a[4]; uint2 v; } xv;
#pragma unroll
      for (int e = 0; e < 4; e++) xv.a[e] = f2h(z[2 * e + 1 - par]);
      *(uint2*)&X[zr * 40 + zq * 4] = xv.v;
    }
    __syncthreads();                          // X visible (also fences prev coupling TS reads)

    for (int net = 0; net < 2; net++) {
      const int idx = layer * 2 + net;

      // ---- H1 = relu(X @ W1 + b1), K=32, wave cols [cw, cw+64) -> bufA
      // swapped mfma: lane holds H1[m = rt*16 + lm, n = cw + ct*16 + quad*4 + g]
      {
        const float* b1p = (net ? sb1 : tb1) + layer * 512 + cw + quad * 4;
        f32x4 bias1[4];
#pragma unroll
        for (int ct = 0; ct < 4; ct++) bias1[ct] = *(const f32x4*)&b1p[ct * 16];
        const u16* W1p = W1T + ((size_t)idx * 512 + cw + lm) * 32 + quad * 8;
        half8 bv[4];
#pragma unroll
        for (int ct = 0; ct < 4; ct++) bv[ct] = *(const half8*)&W1p[ct * 512];
        half8 av[4];
#pragma unroll
        for (int rt = 0; rt < 4; rt++)
          av[rt] = *(const half8*)&X[(rt * 16 + lm) * 40 + quad * 8];
        f32x4 zz = {0.f, 0.f, 0.f, 0.f};
        f32x4 acc[4][4];
#pragma unroll
        for (int rt = 0; rt < 4; rt++)
#pragma unroll
          for (int ct = 0; ct < 4; ct++)
            acc[rt][ct] = __builtin_amdgcn_mfma_f32_16x16x32_f16(bv[ct], av[rt], zz, 0, 0, 0);
        // bufA is free here: prev net's H2 reads of bufA completed before its bar2
#pragma unroll
        for (int rt = 0; rt < 4; rt++) {
          const int m = rt * 16 + lm;
#pragma unroll
          for (int ct = 0; ct < 4; ct++) {
            const int n0 = cw + ct * 16 + quad * 4;
            union { u16 a[4]; uint2 v; } pk;
#pragma unroll
            for (int g = 0; g < 4; g++) {
              float v = acc[rt][ct][g] + bias1[ct][g];
              pk.a[g] = f2h(v > 0.f ? v : 0.f);
            }
            *(uint2*)&bufA[m * 512 + ((((n0 >> 3) ^ (m & 7)) << 3) | (n0 & 7))] = pk.v;
          }
        }
      }
      __syncthreads();                        // bar1: H1 written -> H2 reads

      // ---- H2 = relu(H1 @ W2 + b2), K=512, W2 streamed, depth-3 rotating prefetch
      {
        const float* b2p = (net ? sb2 : tb2) + layer * 512 + cw + quad * 4;
        f32x4 bias2[4];
#pragma unroll
        for (int ct = 0; ct < 4; ct++) bias2[ct] = *(const f32x4*)&b2p[ct * 16];
        const u16* W2p = W2T + ((size_t)idx * 512 + cw + lm) * 512 + quad * 8;
        f32x4 zz = {0.f, 0.f, 0.f, 0.f};
        f32x4 acc[4][4];
#pragma unroll
        for (int rt = 0; rt < 4; rt++)
#pragma unroll
          for (int ct = 0; ct < 4; ct++) acc[rt][ct] = zz;
        half8 bb[3][4];                       // depth-3 rotating prefetch (48 VGPR)
#pragma unroll
        for (int p = 0; p < 3; p++) {
          const int kp = ((p + phase) & 15) * 32;
#pragma unroll
          for (int ct = 0; ct < 4; ct++)
            bb[p][ct] = *(const half8*)&W2p[ct * 8192 + kp];
        }
#pragma unroll
        for (int ci = 0; ci < 16; ci++) {
          const int kk = ((ci + phase) & 15) * 32;
          half8 av[4];
#pragma unroll
          for (int rt = 0; rt < 4; rt++) {
            const int m = rt * 16 + lm;
            av[rt] = *(const half8*)&bufA[m * 512 + ((((kk >> 3) + quad) ^ (m & 7)) << 3)];
          }
#pragma unroll
          for (int rt = 0; rt < 4; rt++)
#pragma unroll
            for (int ct = 0; ct < 4; ct++)
              acc[rt][ct] = __builtin_amdgcn_mfma_f32_16x16x32_f16(bb[ci % 3][ct], av[rt], acc[rt][ct], 0, 0, 0);
          if (ci < 13) {                      // refill consumed slot with chunk ci+3
            const int kn = ((ci + 3 + phase) & 15) * 32;
#pragma unroll
            for (int ct = 0; ct < 4; ct++)
              bb[ci % 3][ct] = *(const half8*)&W2p[ct * 8192 + kn];
          }
        }
        // epilogue writes bufB (b64 packed, bank-balanced) -> no in-place barrier
#pragma unroll
        for (int rt = 0; rt < 4; rt++) {
          const int m = rt * 16 + lm;
#pragma unroll
          for (int ct = 0; ct < 4; ct++) {
            const int n0 = cw + ct * 16 + quad * 4;
            union { u16 a[4]; uint2 v; } pk;
#pragma unroll
            for (int g = 0; g < 4; g++) {
              float v = acc[rt][ct][g] + bias2[ct][g];
              pk.a[g] = f2h(v > 0.f ? v : 0.f);
            }
            *(uint2*)&bufB[m * 512 + ((((n0 >> 3) ^ (m & 7)) << 3) | (n0 & 7))] = pk.v;
          }
        }
      }
      __syncthreads();                        // bar2: bufB visible; bufA reads all done

      // ---- head: wave w -> rows [(w&3)*16,+16), col tile (w>>2)*16, K=512
      // swapped mfma: lane holds out[m = hr + lm, j = hc + quad*4 + g]
      {
        const int hr = (w & 3) * 16, hc = (w >> 2) * 16;
        const u16* W3p = W3T + ((size_t)idx * 32 + hc + lm) * 512 + quad * 8;
        f32x4 ha[2];
        ha[0] = (f32x4){0.f, 0.f, 0.f, 0.f}; ha[1] = ha[0];
        const int m = hr + lm;
        half8 pv[4];                          // depth-4 W3 prefetch
#pragma unroll
        for (int p = 0; p < 4; p++)
          pv[p] = *(const half8*)&W3p[((p + phase) & 15) * 32];
#pragma unroll
        for (int ci = 0; ci < 16; ci++) {
          const int kk = ((ci + phase) & 15) * 32;
          half8 av = *(const half8*)&bufB[m * 512 + ((((kk >> 3) + quad) ^ (m & 7)) << 3)];
          ha[ci & 1] = __builtin_amdgcn_mfma_f32_16x16x32_f16(pv[ci & 3], av, ha[ci & 1], 0, 0, 0);
          if (ci < 12)
            pv[ci & 3] = *(const half8*)&W3p[((ci + 4 + phase) & 15) * 32];
        }
        const int j0 = hc + quad * 4;
        if (net == 0) {
          const f32x4 b3 = *(const f32x4*)&tb3[layer * 32 + j0];
#pragma unroll
          for (int g = 0; g < 4; g++)
            TS[m * 68 + 2 * (j0 + g)] = ha[0][g] + ha[1][g] + b3[g];
        } else {
          const f32x4 b3 = *(const f32x4*)&sb3[layer * 32 + j0];
          const f32x4 sc = *(const f32x4*)&s_scale[layer * 32 + j0];
          const f32x4 sh = *(const f32x4*)&s_shift[layer * 32 + j0];
#pragma unroll
          for (int g = 0; g < 4; g++)
            TS[m * 68 + 2 * (j0 + g) + 1] = tanhf(ha[0][g] + ha[1][g] + b3[g]) * sc[g] + sh[g];
        }
      }
      __syncthreads();                        // bar3: bufB reads done; TS visible
    } // net

    // ---- coupling: thread reads its 4 (t,s) pairs, updates z/ld in registers.
    // (No trailing barrier: next layer's X barrier orders these TS reads
    //  before the next head's TS writes.)
    {
      const float* base = &TS[zr * 68 + zq * 8];
      f32x4 q0 = *(const f32x4*)&base[0];
      f32x4 q1 = *(const f32x4*)&base[4];
      float q[8];
#pragma unroll
      for (int k = 0; k < 4; k++) { q[k] = q0[k]; q[4 + k] = q1[k]; }
#pragma unroll
      for (int e = 0; e < 4; e++) {
        const float tv = q[2 * e], sv = q[2 * e + 1];
        const int zi = 2 * e + par;
        z[zi] = z[zi] * expf(sv) + tv;
        ld[zi] += sv;
      }
    }
  } // layer

  // ---- store z and log_det
  {
    float* zb = out + (size_t)(m0 + zr) * 64 + c0;
    float* lb = out + (size_t)NBATCH * 64 + (size_t)(m0 + zr) * 64 + c0;
    f32x4 v0, v1, l0, l1;
#pragma unroll
    for (int k = 0; k < 4; k++) {
      v0[k] = z[k]; v1[k] = z[4 + k];
      l0[k] = ld[k]; l1[k] = ld[4 + k];
    }
    *(f32x4*)&zb[0] = v0; *(f32x4*)&zb[4] = v1;
    *(f32x4*)&lb[0] = l0; *(f32x4*)&lb[4] = l1;
  }
}

extern "C" void kernel_launch(void* const* d_in, const int* in_sizes, int n_in,
                              void* d_out, int out_size, void* d_ws, size_t ws_size,
                              hipStream_t stream) {
  (void)in_sizes; (void)n_in; (void)out_size; (void)ws_size;
  const float* y   = (const float*)d_in[0];
  const float* tW1 = (const float*)d_in[1];
  const float* tb1 = (const float*)d_in[2];
  const float* tW2 = (const float*)d_in[3];
  const float* tb2 = (const float*)d_in[4];
  const float* tW3 = (const float*)d_in[5];
  const float* tb3 = (const float*)d_in[6];
  const float* sW1 = (const float*)d_in[7];
  const float* sb1 = (const float*)d_in[8];
  const float* sW2 = (const float*)d_in[9];
  const float* sb2 = (const float*)d_in[10];
  const float* sW3 = (const float*)d_in[11];
  const float* sb3 = (const float*)d_in[12];
  const float* s_scale = (const float*)d_in[13];
  const float* s_shift = (const float*)d_in[14];
  float* out = (float*)d_out;

  char* ws = (char*)d_ws;
  const size_t W1SZ = (size_t)16 * 512 * 32 * 2;    // 524288
  const size_t W2SZ = (size_t)16 * 512 * 512 * 2;   // 8388608
  u16* W1 = (u16*)(ws);
  u16* W2 = (u16*)(ws + W1SZ);
  u16* W3 = (u16*)(ws + W1SZ + W2SZ);

  cvt_all<<<dim3(288, 1, 16), dim3(32, 8), 0, stream>>>(tW1, sW1, tW2, sW2, tW3, sW3,
                                                        W1, W2, W3);

  meganvp<<<256, 512, 0, stream>>>(y, W1, W2, W3, tb1, sb1, tb2, sb2, tb3, sb3,
                                   s_scale, s_shift, out);
}